// Round 2
// baseline (172476.880 us; speedup 1.0000x reference)
//
#include <hip/hip_runtime.h>
#include <hip/hip_bf16.h>
#include <cstdint>
#include <cstddef>

#define N_NODES 50000
#define N_EDGES 200000
#define N_GRAPH 2048
#define DD 256
#define HH 512
#define LL 12
#define NODE_IN_F 173
#define EDGE_IN_F 13
#define ECH 25000   // edge/node row chunk for hidden buffers

typedef __hip_bfloat16 bf16;

// ---------------------------------------------------------------------------
// Multi-part gather GEMM:
//   C[M,N] = act( sum_p A_p[idx_p ? idx_p[r] : r, :K_p] @ B_p + bias ) (+ res)
// A_p is bf16 or fp32 (af32 flag); B_p fp32 [K_p, N] row-major; acc fp32.
// ---------------------------------------------------------------------------
#define BM 64
#define BN 64
#define BK 16

struct G4Args {
    const void* A[4];
    const int*  idx[4];
    const float* B[4];
    int K[4];
    int af32[4];
    int lda[4];
    int nparts;
    int M, N;           // ldc == N, ldb == N
    const float* bias;
    const void* res; int res_f32;
    void* C; int c_f32;
    int relu;
};

__global__ __launch_bounds__(256)
void gemm4(G4Args g)
{
    __shared__ float As[BK][BM + 1];
    __shared__ float Bs[BK][BN + 1];
    const int tid = threadIdx.x;
    const int tx = tid & 15;   // -> N
    const int ty = tid >> 4;   // -> M
    const int row0 = blockIdx.y * BM;
    const int col0 = blockIdx.x * BN;
    float acc[4][4] = {};

    for (int p = 0; p < g.nparts; ++p) {
        const bf16*  Ab  = (const bf16*)g.A[p];
        const float* Af  = (const float*)g.A[p];
        const int*   idx = g.idx[p];
        const float* B   = g.B[p];
        const int Kp = g.K[p];
        const int lda = g.lda[p];
        const int af32 = g.af32[p];

        for (int k0 = 0; k0 < Kp; k0 += BK) {
            // A tile: 64 rows x 16 cols
#pragma unroll
            for (int l = 0; l < 4; ++l) {
                int q = tid + l * 256;
                int r = q >> 4;
                int c = q & 15;
                int gr = row0 + r, gc = k0 + c;
                float v = 0.f;
                if (gr < g.M && gc < Kp) {
                    int ar = idx ? idx[gr] : gr;
                    size_t o = (size_t)ar * lda + gc;
                    v = af32 ? Af[o] : __bfloat162float(Ab[o]);
                }
                As[c][r] = v;
            }
            // B tile: 16 rows x 64 cols
#pragma unroll
            for (int l = 0; l < 4; ++l) {
                int q = tid + l * 256;
                int r = q >> 6;
                int c = q & 63;
                int gr = k0 + r, gc = col0 + c;
                Bs[r][c] = (gr < Kp && gc < g.N) ? B[(size_t)gr * g.N + gc] : 0.f;
            }
            __syncthreads();
#pragma unroll
            for (int kk = 0; kk < BK; ++kk) {
                float a[4], b[4];
#pragma unroll
                for (int i = 0; i < 4; ++i) a[i] = As[kk][ty * 4 + i];
#pragma unroll
                for (int j = 0; j < 4; ++j) b[j] = Bs[kk][tx * 4 + j];
#pragma unroll
                for (int i = 0; i < 4; ++i)
#pragma unroll
                    for (int j = 0; j < 4; ++j)
                        acc[i][j] += a[i] * b[j];
            }
            __syncthreads();
        }
    }

#pragma unroll
    for (int i = 0; i < 4; ++i) {
        int r = row0 + ty * 4 + i;
        if (r >= g.M) continue;
#pragma unroll
        for (int j = 0; j < 4; ++j) {
            int c = col0 + tx * 4 + j;
            if (c >= g.N) continue;
            size_t o = (size_t)r * g.N + c;
            float v = acc[i][j];
            if (g.bias) v += g.bias[c];
            if (g.relu) v = fmaxf(v, 0.f);
            if (g.res)
                v += g.res_f32 ? ((const float*)g.res)[o]
                               : __bfloat162float(((const bf16*)g.res)[o]);
            if (g.c_f32) ((float*)g.C)[o] = v;
            else         ((bf16*)g.C)[o] = __float2bfloat16(v);
        }
    }
}

// host-side builders
static inline G4Args g4_new(int M, int N) {
    G4Args g;
    for (int i = 0; i < 4; ++i) { g.A[i] = nullptr; g.idx[i] = nullptr; g.B[i] = nullptr; g.K[i] = 0; g.af32[i] = 0; g.lda[i] = 0; }
    g.nparts = 0; g.M = M; g.N = N;
    g.bias = nullptr; g.res = nullptr; g.res_f32 = 0; g.C = nullptr; g.c_f32 = 0; g.relu = 0;
    return g;
}
static inline void g4_part(G4Args& g, const void* A, int lda, const int* idx,
                           const float* B, int K, int af32) {
    int p = g.nparts++;
    g.A[p] = A; g.lda[p] = lda; g.idx[p] = idx; g.B[p] = B; g.K[p] = K; g.af32[p] = af32;
}
static inline void g4_run(hipStream_t s, G4Args& g, const float* bias,
                          const void* res, int res_f32, void* C, int c_f32, int relu) {
    g.bias = bias; g.res = res; g.res_f32 = res_f32; g.C = C; g.c_f32 = c_f32; g.relu = relu;
    dim3 grid((g.N + BN - 1) / BN, (g.M + BM - 1) / BM);
    gemm4<<<grid, dim3(256), 0, s>>>(g);
}

// ---------------------------------------------------------------------------
// graph structure helpers
// ---------------------------------------------------------------------------
__global__ void zero_i32(int* __restrict__ p, int n) {
    int i = blockIdx.x * blockDim.x + threadIdx.x;
    if (i < n) p[i] = 0;
}
__global__ void copy_i32(const int* __restrict__ a, int* __restrict__ b, int n) {
    int i = blockIdx.x * blockDim.x + threadIdx.x;
    if (i < n) b[i] = a[i];
}
__global__ void count_edges(const int* __restrict__ src, const int* __restrict__ dst,
                            const int* __restrict__ node_batch,
                            int* __restrict__ cnt_s, int* __restrict__ cnt_d,
                            int* __restrict__ ebat)
{
    int i = blockIdx.x * blockDim.x + threadIdx.x;
    if (i >= N_EDGES) return;
    int s = src[i], d = dst[i];
    atomicAdd(&cnt_s[s], 1);
    atomicAdd(&cnt_d[d], 1);
    ebat[i] = node_batch[s];
}
__global__ void count_nodes(const int* __restrict__ node_batch, int* __restrict__ gcnt)
{
    int i = blockIdx.x * blockDim.x + threadIdx.x;
    if (i >= N_NODES) return;
    atomicAdd(&gcnt[node_batch[i]], 1);
}
// single-block exclusive scan: off[0..n] from cnt[0..n-1], off[n]=total
__global__ __launch_bounds__(1024)
void scan_excl_kernel(const int* __restrict__ cnt, int* __restrict__ off, int n)
{
    __shared__ int part[1024];
    int t = threadIdx.x;
    int chunk = (n + 1023) >> 10;
    int lo = t * chunk; if (lo > n) lo = n;
    int hi = lo + chunk; if (hi > n) hi = n;
    int s = 0;
    for (int i = lo; i < hi; ++i) s += cnt[i];
    part[t] = s;
    __syncthreads();
    for (int d = 1; d < 1024; d <<= 1) {
        int v = (t >= d) ? part[t - d] : 0;
        __syncthreads();
        part[t] += v;
        __syncthreads();
    }
    int base = (t == 0) ? 0 : part[t - 1];
    for (int i = lo; i < hi; ++i) { off[i] = base; base += cnt[i]; }
    if (t == 1023) off[n] = part[1023];
}
__global__ void csr_fill(const int* __restrict__ src, const int* __restrict__ dst,
                         int* __restrict__ cur_s, int* __restrict__ cur_d,
                         int* __restrict__ idx_s, int* __restrict__ idx_d)
{
    int i = blockIdx.x * blockDim.x + threadIdx.x;
    if (i >= N_EDGES) return;
    int p = atomicAdd(&cur_s[src[i]], 1); idx_s[p] = i;
    int q = atomicAdd(&cur_d[dst[i]], 1); idx_d[q] = i;
}

// out[n,:] = sum_{k in [off[n],off[n+1])} rows[idx[k],:]   (DD cols, block=256)
__global__ void seg_sum_csr(const bf16* __restrict__ rows, const int* __restrict__ offs,
                            const int* __restrict__ idx, bf16* __restrict__ out)
{
    int n = blockIdx.x;
    int c = threadIdx.x;
    int k0 = offs[n], k1 = offs[n + 1];
    float s = 0.f;
    for (int k = k0; k < k1; ++k) s += __bfloat162float(rows[(size_t)idx[k] * DD + c]);
    out[(size_t)n * DD + c] = __float2bfloat16(s);
}
// out[g,:] = sum_{n in [gs[g],gs[g+1])} rows[n,:]
__global__ void range_sum(const bf16* __restrict__ rows, const int* __restrict__ gs,
                          bf16* __restrict__ out)
{
    int g = blockIdx.x;
    int c = threadIdx.x;
    int n0 = gs[g], n1 = gs[g + 1];
    float s = 0.f;
    for (int n = n0; n < n1; ++n) s += __bfloat162float(rows[(size_t)n * DD + c]);
    out[(size_t)g * DD + c] = __float2bfloat16(s);
}

__global__ void u_init(bf16* __restrict__ u, const float* __restrict__ u0)
{
    int i = blockIdx.x * blockDim.x + threadIdx.x;
    if (i < N_GRAPH * DD) u[i] = __float2bfloat16(u0[i & (DD - 1)]);
}

// pos[row,:] (+)= ph[row,:] @ W[256,3] + b[3]; one wave per row
__global__ void pos_head2(const bf16* __restrict__ ph, const float* __restrict__ W,
                          const float* __restrict__ b, float* __restrict__ pos,
                          int nrows, int write_mode)
{
    int gid = blockIdx.x * blockDim.x + threadIdx.x;
    int row = gid >> 6;
    int lane = threadIdx.x & 63;
    if (row >= nrows) return;
    const bf16* r = ph + (size_t)row * DD;
    float a0 = 0.f, a1 = 0.f, a2 = 0.f;
    for (int k = lane; k < DD; k += 64) {
        float v = __bfloat162float(r[k]);
        a0 += v * W[k * 3 + 0];
        a1 += v * W[k * 3 + 1];
        a2 += v * W[k * 3 + 2];
    }
#pragma unroll
    for (int d = 32; d > 0; d >>= 1) {
        a0 += __shfl_down(a0, d);
        a1 += __shfl_down(a1, d);
        a2 += __shfl_down(a2, d);
    }
    if (lane == 0) {
        float* p = pos + (size_t)row * 3;
        if (write_mode) {
            p[0] = a0 + b[0]; p[1] = a1 + b[1]; p[2] = a2 + b[2];
        } else {
            p[0] += a0 + b[0]; p[1] += a1 + b[1]; p[2] += a2 + b[2];
        }
    }
}

// ---------------------------------------------------------------------------
extern "C" void kernel_launch(void* const* d_in, const int* in_sizes, int n_in,
                              void* d_out, int out_size, void* d_ws, size_t ws_size,
                              hipStream_t stream)
{
    const float* x_raw    = (const float*)d_in[0];
    const float* edge_raw = (const float*)d_in[1];
    const float* u0       = (const float*)d_in[2];
    const float* enW1 = (const float*)d_in[3];  const float* enb1 = (const float*)d_in[4];
    const float* enW2 = (const float*)d_in[5];  const float* enb2 = (const float*)d_in[6];
    const float* enW3 = (const float*)d_in[7];  const float* enb3 = (const float*)d_in[8];
    const float* eeW1 = (const float*)d_in[9];  const float* eeb1 = (const float*)d_in[10];
    const float* eeW2 = (const float*)d_in[11]; const float* eeb2 = (const float*)d_in[12];
    const float* eeW3 = (const float*)d_in[13]; const float* eeb3 = (const float*)d_in[14];
    const float* eW1 = (const float*)d_in[15];  const float* eb1 = (const float*)d_in[16];
    const float* eW2 = (const float*)d_in[17];  const float* eb2 = (const float*)d_in[18];
    const float* eW3 = (const float*)d_in[19];  const float* eb3 = (const float*)d_in[20];
    const float* nW1 = (const float*)d_in[21];  const float* nb1 = (const float*)d_in[22];
    const float* nW2 = (const float*)d_in[23];  const float* nb2 = (const float*)d_in[24];
    const float* nW3 = (const float*)d_in[25];  const float* nb3 = (const float*)d_in[26];
    const float* gW1 = (const float*)d_in[27];  const float* gb1 = (const float*)d_in[28];
    const float* gW2 = (const float*)d_in[29];  const float* gb2 = (const float*)d_in[30];
    const float* gW3 = (const float*)d_in[31];  const float* gb3 = (const float*)d_in[32];
    const float* pW1 = (const float*)d_in[33];  const float* pb1 = (const float*)d_in[34];
    const float* pW2 = (const float*)d_in[35];  const float* pb2 = (const float*)d_in[36];
    const int* edge_index = (const int*)d_in[37];
    const int* node_batch = (const int*)d_in[38];
    const int* src = edge_index;
    const int* dst = edge_index + N_EDGES;
    float* pos = (float*)d_out;
    (void)ws_size; (void)in_sizes; (void)n_in; (void)out_size;

    // ---- workspace carve (bf16 activations; total ~236 MB) ----
    char* wp = (char*)d_ws;
    auto alloc = [&](size_t bytes) -> void* {
        void* r = (void*)wp;
        wp += (bytes + 255) & ~(size_t)255;
        return r;
    };
    bf16* x    = (bf16*)alloc((size_t)N_NODES * DD * 2);
    bf16* e    = (bf16*)alloc((size_t)N_EDGES * DD * 2);
    bf16* u    = (bf16*)alloc((size_t)N_GRAPH * DD * 2);
    bf16* h1   = (bf16*)alloc((size_t)ECH * HH * 2);
    bf16* h2   = (bf16*)alloc((size_t)ECH * HH * 2);
    bf16* sent = (bf16*)alloc((size_t)N_NODES * DD * 2);
    bf16* recv = (bf16*)alloc((size_t)N_NODES * DD * 2);
    bf16* gn   = (bf16*)alloc((size_t)N_GRAPH * DD * 2);
    bf16* ge   = (bf16*)alloc((size_t)N_GRAPH * DD * 2);
    bf16* gh1  = (bf16*)alloc((size_t)N_GRAPH * HH * 2);
    bf16* gh2  = (bf16*)alloc((size_t)N_GRAPH * HH * 2);
    int* cnt_s  = (int*)alloc((size_t)N_NODES * 4);
    int* cnt_d  = (int*)alloc((size_t)N_NODES * 4);
    int* gcnt   = (int*)alloc((size_t)N_GRAPH * 4);
    int* off_s  = (int*)alloc((size_t)(N_NODES + 1) * 4);
    int* off_d  = (int*)alloc((size_t)(N_NODES + 1) * 4);
    int* gstart = (int*)alloc((size_t)(N_GRAPH + 1) * 4);
    int* cur_s  = (int*)alloc((size_t)N_NODES * 4);
    int* cur_d  = (int*)alloc((size_t)N_NODES * 4);
    int* idx_s  = (int*)alloc((size_t)N_EDGES * 4);
    int* idx_d  = (int*)alloc((size_t)N_EDGES * 4);
    int* ebat   = (int*)alloc((size_t)N_EDGES * 4);

    // ---- graph structure (rebuilt every call) ----
    zero_i32<<<(N_NODES + 255) / 256, 256, 0, stream>>>(cnt_s, N_NODES);
    zero_i32<<<(N_NODES + 255) / 256, 256, 0, stream>>>(cnt_d, N_NODES);
    zero_i32<<<(N_GRAPH + 255) / 256, 256, 0, stream>>>(gcnt, N_GRAPH);
    count_edges<<<(N_EDGES + 255) / 256, 256, 0, stream>>>(src, dst, node_batch, cnt_s, cnt_d, ebat);
    count_nodes<<<(N_NODES + 255) / 256, 256, 0, stream>>>(node_batch, gcnt);
    scan_excl_kernel<<<1, 1024, 0, stream>>>(cnt_s, off_s, N_NODES);
    scan_excl_kernel<<<1, 1024, 0, stream>>>(cnt_d, off_d, N_NODES);
    scan_excl_kernel<<<1, 1024, 0, stream>>>(gcnt, gstart, N_GRAPH);
    copy_i32<<<(N_NODES + 255) / 256, 256, 0, stream>>>(off_s, cur_s, N_NODES);
    copy_i32<<<(N_NODES + 255) / 256, 256, 0, stream>>>(off_d, cur_d, N_NODES);
    csr_fill<<<(N_EDGES + 255) / 256, 256, 0, stream>>>(src, dst, cur_s, cur_d, idx_s, idx_d);

    u_init<<<(N_GRAPH * DD + 255) / 256, 256, 0, stream>>>(u, u0);

    // ---- node encoder (chunks of ECH) ----
    for (int off = 0; off < N_NODES; off += ECH) {
        int cnt = (N_NODES - off < ECH) ? (N_NODES - off) : ECH;
        { G4Args g = g4_new(cnt, HH); g4_part(g, x_raw + (size_t)off * NODE_IN_F, NODE_IN_F, nullptr, enW1, NODE_IN_F, 1);
          g4_run(stream, g, enb1, nullptr, 0, h1, 0, 1); }
        { G4Args g = g4_new(cnt, HH); g4_part(g, h1, HH, nullptr, enW2, HH, 0);
          g4_run(stream, g, enb2, nullptr, 0, h2, 0, 1); }
        { G4Args g = g4_new(cnt, DD); g4_part(g, h2, HH, nullptr, enW3, HH, 0);
          g4_run(stream, g, enb3, nullptr, 0, x + (size_t)off * DD, 0, 1); }
    }
    // ---- edge encoder ----
    for (int off = 0; off < N_EDGES; off += ECH) {
        int cnt = (N_EDGES - off < ECH) ? (N_EDGES - off) : ECH;
        { G4Args g = g4_new(cnt, HH); g4_part(g, edge_raw + (size_t)off * EDGE_IN_F, EDGE_IN_F, nullptr, eeW1, EDGE_IN_F, 1);
          g4_run(stream, g, eeb1, nullptr, 0, h1, 0, 1); }
        { G4Args g = g4_new(cnt, HH); g4_part(g, h1, HH, nullptr, eeW2, HH, 0);
          g4_run(stream, g, eeb2, nullptr, 0, h2, 0, 1); }
        { G4Args g = g4_new(cnt, DD); g4_part(g, h2, HH, nullptr, eeW3, HH, 0);
          g4_run(stream, g, eeb3, nullptr, 0, e + (size_t)off * DD, 0, 1); }
    }

    // ---- L message-passing layers ----
    for (int l = 0; l < LL; ++l) {
        const float* ew1  = eW1 + (size_t)l * 4 * DD * HH;  const float* eb1l = eb1 + (size_t)l * HH;
        const float* ew2  = eW2 + (size_t)l * HH * HH;      const float* eb2l = eb2 + (size_t)l * HH;
        const float* ew3  = eW3 + (size_t)l * HH * DD;      const float* eb3l = eb3 + (size_t)l * DD;
        const float* nw1  = nW1 + (size_t)l * 4 * DD * HH;  const float* nb1l = nb1 + (size_t)l * HH;
        const float* nw2  = nW2 + (size_t)l * HH * HH;      const float* nb2l = nb2 + (size_t)l * HH;
        const float* nw3  = nW3 + (size_t)l * HH * DD;      const float* nb3l = nb3 + (size_t)l * DD;
        const float* gw1  = gW1 + (size_t)l * 3 * DD * HH;  const float* gb1l = gb1 + (size_t)l * HH;
        const float* gw2  = gW2 + (size_t)l * HH * HH;      const float* gb2l = gb2 + (size_t)l * HH;
        const float* gw3  = gW3 + (size_t)l * HH * DD;      const float* gb3l = gb3 + (size_t)l * DD;
        const float* pw1  = pW1 + (size_t)l * DD * DD;      const float* pb1l = pb1 + (size_t)l * DD;
        const float* pw2  = pW2 + (size_t)l * DD * 3;       const float* pb2l = pb2 + (size_t)l * 3;

        // ---- edge update: e += MLP3(concat[e, x[src], x[dst], u[eb]]) ----
        for (int off = 0; off < N_EDGES; off += ECH) {
            int cnt = (N_EDGES - off < ECH) ? (N_EDGES - off) : ECH;
            { G4Args g = g4_new(cnt, HH);
              g4_part(g, e + (size_t)off * DD, DD, nullptr,    ew1,                    DD, 0);
              g4_part(g, x,                    DD, src + off,  ew1 + (size_t)1*DD*HH,  DD, 0);
              g4_part(g, x,                    DD, dst + off,  ew1 + (size_t)2*DD*HH,  DD, 0);
              g4_part(g, u,                    DD, ebat + off, ew1 + (size_t)3*DD*HH,  DD, 0);
              g4_run(stream, g, eb1l, nullptr, 0, h1, 0, 1); }
            { G4Args g = g4_new(cnt, HH); g4_part(g, h1, HH, nullptr, ew2, HH, 0);
              g4_run(stream, g, eb2l, nullptr, 0, h2, 0, 1); }
            { G4Args g = g4_new(cnt, DD); g4_part(g, h2, HH, nullptr, ew3, HH, 0);
              g4_run(stream, g, eb3l, e + (size_t)off * DD, 0, e + (size_t)off * DD, 0, 1); }
        }

        // ---- node update ----
        seg_sum_csr<<<N_NODES, 256, 0, stream>>>(e, off_s, idx_s, sent);
        seg_sum_csr<<<N_NODES, 256, 0, stream>>>(e, off_d, idx_d, recv);
        for (int off = 0; off < N_NODES; off += ECH) {
            int cnt = (N_NODES - off < ECH) ? (N_NODES - off) : ECH;
            { G4Args g = g4_new(cnt, HH);
              g4_part(g, x    + (size_t)off * DD, DD, nullptr,          nw1,                   DD, 0);
              g4_part(g, sent + (size_t)off * DD, DD, nullptr,          nw1 + (size_t)1*DD*HH, DD, 0);
              g4_part(g, recv + (size_t)off * DD, DD, nullptr,          nw1 + (size_t)2*DD*HH, DD, 0);
              g4_part(g, u,                       DD, node_batch + off, nw1 + (size_t)3*DD*HH, DD, 0);
              g4_run(stream, g, nb1l, nullptr, 0, h1, 0, 1); }
            { G4Args g = g4_new(cnt, HH); g4_part(g, h1, HH, nullptr, nw2, HH, 0);
              g4_run(stream, g, nb2l, nullptr, 0, h2, 0, 1); }
            { G4Args g = g4_new(cnt, DD); g4_part(g, h2, HH, nullptr, nw3, HH, 0);
              g4_run(stream, g, nb3l, x + (size_t)off * DD, 0, x + (size_t)off * DD, 0, 1); }
        }

        // ---- global update (ge == range-sum of `sent`, since edge_batch=node_batch[src]) ----
        range_sum<<<N_GRAPH, 256, 0, stream>>>(x, gstart, gn);
        range_sum<<<N_GRAPH, 256, 0, stream>>>(sent, gstart, ge);
        { G4Args g = g4_new(N_GRAPH, HH);
          g4_part(g, u,  DD, nullptr, gw1,                   DD, 0);
          g4_part(g, gn, DD, nullptr, gw1 + (size_t)1*DD*HH, DD, 0);
          g4_part(g, ge, DD, nullptr, gw1 + (size_t)2*DD*HH, DD, 0);
          g4_run(stream, g, gb1l, nullptr, 0, gh1, 0, 1); }
        { G4Args g = g4_new(N_GRAPH, HH); g4_part(g, gh1, HH, nullptr, gw2, HH, 0);
          g4_run(stream, g, gb2l, nullptr, 0, gh2, 0, 1); }
        { G4Args g = g4_new(N_GRAPH, DD); g4_part(g, gh2, HH, nullptr, gw3, HH, 0);
          g4_run(stream, g, gb3l, u, 0, u, 0, 1); }

        // ---- position head (reuse h1 as [cnt, DD] buffer) ----
        for (int off = 0; off < N_NODES; off += ECH) {
            int cnt = (N_NODES - off < ECH) ? (N_NODES - off) : ECH;
            { G4Args g = g4_new(cnt, DD); g4_part(g, x + (size_t)off * DD, DD, nullptr, pw1, DD, 0);
              g4_run(stream, g, pb1l, nullptr, 0, h1, 0, 1); }
            pos_head2<<<((size_t)cnt * 64 + 255) / 256, 256, 0, stream>>>(
                h1, pw2, pb2l, pos + (size_t)off * 3, cnt, l == 0 ? 1 : 0);
        }
    }
}

// Round 3
// 38843.039 us; speedup vs baseline: 4.4404x; 4.4404x over previous
//
#include <hip/hip_runtime.h>
#include <hip/hip_bf16.h>
#include <cstdint>
#include <cstddef>

#define N_NODES 50000
#define N_EDGES 200000
#define N_GRAPH 2048
#define DD 256
#define HH 512
#define LL 12
#define NODE_IN_F 173
#define EDGE_IN_F 13
#define RCH 12500   // row chunk (nodes: 4 chunks, edges: 16 chunks)

typedef __hip_bfloat16 bf16;
typedef __attribute__((ext_vector_type(8))) short short8;
typedef __attribute__((ext_vector_type(4))) float f32x4;

// ---------------------------------------------------------------------------
// MFMA multi-part gather GEMM with hi/lo-split bf16 weights.
//   C[M,N] = act( sum_p A_p[idx_p? idx_p[r]:r, :Kp] @ (Whi_p + Wlo_p)^T + bias ) (+res)
// A_p bf16 row-major [.,lda]; Whi/Wlo bf16 [N][ldw] (transposed weights, K-padded).
// ---------------------------------------------------------------------------
#define TBM 128
#define TBN 128
#define LDAP 40   // padded LDS row length (shorts): 32 + 8 -> 2-way bank aliasing only

struct GMArgs {
    const bf16* A[4];
    const int*  idx[4];
    const bf16* whi[4];
    const bf16* wlo[4];
    int lda[4];
    int ldw[4];
    int Kp[4];
    int nparts;
    int M, N;            // ldc == N
    const float* bias;
    const bf16* res;     // row stride N
    bf16* C;
    int relu;
};

__global__ __launch_bounds__(256)
void gemm_mfma(GMArgs g)
{
    __shared__ __align__(16) short As[TBM * LDAP];
    __shared__ __align__(16) short Bh[TBN * LDAP];
    __shared__ __align__(16) short Bl[TBN * LDAP];

    const int tid  = threadIdx.x;
    const int lane = tid & 63;
    const int wv   = tid >> 6;
    const int wm   = (wv >> 1) * 64;   // wave row offset in tile
    const int wn   = (wv & 1) * 64;    // wave col offset in tile
    const int quad = lane >> 4;
    const int l16  = lane & 15;
    const int row0 = blockIdx.y * TBM;
    const int col0 = blockIdx.x * TBN;

    f32x4 acc[4][4];
#pragma unroll
    for (int i = 0; i < 4; ++i)
#pragma unroll
        for (int j = 0; j < 4; ++j)
            acc[i][j] = (f32x4){0.f, 0.f, 0.f, 0.f};

    for (int p = 0; p < g.nparts; ++p) {
        const short* Ap  = (const short*)g.A[p];
        const short* Whi = (const short*)g.whi[p];
        const short* Wlo = (const short*)g.wlo[p];
        const int* idx = g.idx[p];
        const int lda = g.lda[p];
        const int ldw = g.ldw[p];
        const int Kp  = g.Kp[p];

        for (int k0 = 0; k0 < Kp; k0 += 32) {
            __syncthreads();   // protect LDS from previous iteration's readers
#pragma unroll
            for (int t = 0; t < 2; ++t) {
                int q4 = tid + t * 256;      // 0..511
                int r  = q4 >> 2;            // tile row 0..127
                int q  = q4 & 3;             // 16B quarter within the 64B row-slab
                // A tile
                int4 va = {0, 0, 0, 0};
                int gr = row0 + r;
                if (gr < g.M) {
                    int ar = idx ? idx[gr] : gr;
                    va = *(const int4*)(Ap + (size_t)ar * lda + k0 + q * 8);
                }
                *(int4*)&As[r * LDAP + q * 8] = va;
                // B tiles (N is a multiple of 128 -> no col guard)
                size_t wo = (size_t)(col0 + r) * ldw + k0 + q * 8;
                *(int4*)&Bh[r * LDAP + q * 8] = *(const int4*)(Whi + wo);
                *(int4*)&Bl[r * LDAP + q * 8] = *(const int4*)(Wlo + wo);
            }
            __syncthreads();

            short8 a[4], bh[4], bl[4];
#pragma unroll
            for (int i = 0; i < 4; ++i)
                a[i] = *(const short8*)&As[(wm + i * 16 + l16) * LDAP + quad * 8];
#pragma unroll
            for (int j = 0; j < 4; ++j) {
                bh[j] = *(const short8*)&Bh[(wn + j * 16 + l16) * LDAP + quad * 8];
                bl[j] = *(const short8*)&Bl[(wn + j * 16 + l16) * LDAP + quad * 8];
            }
#pragma unroll
            for (int i = 0; i < 4; ++i)
#pragma unroll
                for (int j = 0; j < 4; ++j)
                    acc[i][j] = __builtin_amdgcn_mfma_f32_16x16x32_bf16(a[i], bh[j], acc[i][j], 0, 0, 0);
#pragma unroll
            for (int i = 0; i < 4; ++i)
#pragma unroll
                for (int j = 0; j < 4; ++j)
                    acc[i][j] = __builtin_amdgcn_mfma_f32_16x16x32_bf16(a[i], bl[j], acc[i][j], 0, 0, 0);
        }
    }

    // epilogue: C/D frag mapping col=lane&15, row=quad*4+reg
#pragma unroll
    for (int j = 0; j < 4; ++j) {
        int c = col0 + wn + j * 16 + l16;
        float bc = g.bias ? g.bias[c] : 0.f;
#pragma unroll
        for (int i = 0; i < 4; ++i) {
            int rbase = row0 + wm + i * 16 + quad * 4;
#pragma unroll
            for (int r = 0; r < 4; ++r) {
                int gr = rbase + r;
                if (gr >= g.M) continue;
                float v = acc[i][j][r] + bc;
                if (g.relu) v = fmaxf(v, 0.f);
                size_t o = (size_t)gr * g.N + c;
                if (g.res) v += __bfloat162float(g.res[o]);
                g.C[o] = __float2bfloat16(v);
            }
        }
    }
}

// host-side builders
static inline GMArgs gm_new(int M, int N) {
    GMArgs g;
    for (int i = 0; i < 4; ++i) { g.A[i] = nullptr; g.idx[i] = nullptr; g.whi[i] = nullptr; g.wlo[i] = nullptr; g.lda[i] = 0; g.ldw[i] = 0; g.Kp[i] = 0; }
    g.nparts = 0; g.M = M; g.N = N; g.bias = nullptr; g.res = nullptr; g.C = nullptr; g.relu = 0;
    return g;
}
static inline void gm_part(GMArgs& g, const bf16* A, int lda, const int* idx,
                           const bf16* whi, const bf16* wlo, int ldw, int Kp) {
    int p = g.nparts++;
    g.A[p] = A; g.lda[p] = lda; g.idx[p] = idx; g.whi[p] = whi; g.wlo[p] = wlo; g.ldw[p] = ldw; g.Kp[p] = Kp;
}
static inline void gm_run(hipStream_t s, GMArgs& g, const float* bias,
                          const bf16* res, bf16* C, int relu) {
    g.bias = bias; g.res = res; g.C = C; g.relu = relu;
    dim3 grid(g.N / TBN, (g.M + TBM - 1) / TBM);
    gemm_mfma<<<grid, dim3(256), 0, s>>>(g);
}

// ---------------------------------------------------------------------------
// weight convert: W fp32 [K][N] -> Whi/Wlo bf16 [N][Kp] (transposed, zero-padded)
// ---------------------------------------------------------------------------
__global__ void conv_w(const float* __restrict__ W, int N, int K, int Kp,
                       bf16* __restrict__ hi, bf16* __restrict__ lo)
{
    int i = blockIdx.x * blockDim.x + threadIdx.x;
    if (i >= N * Kp) return;
    int n = i / Kp, k = i % Kp;
    float v = (k < K) ? W[(size_t)k * N + n] : 0.f;
    bf16 h = __float2bfloat16(v);
    hi[i] = h;
    lo[i] = __float2bfloat16(v - __bfloat162float(h));
}

// pad raw fp32 rows [rows][K] -> bf16 [rows][Kp] zero-padded
__global__ void pad_raw(const float* __restrict__ src, int K, int Kp, int rows,
                        bf16* __restrict__ out)
{
    int i = blockIdx.x * blockDim.x + threadIdx.x;
    if (i >= rows * Kp) return;
    int r = i / Kp, k = i % Kp;
    out[i] = __float2bfloat16(k < K ? src[(size_t)r * K + k] : 0.f);
}

// ---------------------------------------------------------------------------
// graph structure helpers (unchanged from round 2)
// ---------------------------------------------------------------------------
__global__ void zero_i32(int* __restrict__ p, int n) {
    int i = blockIdx.x * blockDim.x + threadIdx.x;
    if (i < n) p[i] = 0;
}
__global__ void copy_i32(const int* __restrict__ a, int* __restrict__ b, int n) {
    int i = blockIdx.x * blockDim.x + threadIdx.x;
    if (i < n) b[i] = a[i];
}
__global__ void count_edges(const int* __restrict__ src, const int* __restrict__ dst,
                            const int* __restrict__ node_batch,
                            int* __restrict__ cnt_s, int* __restrict__ cnt_d,
                            int* __restrict__ ebat)
{
    int i = blockIdx.x * blockDim.x + threadIdx.x;
    if (i >= N_EDGES) return;
    int s = src[i], d = dst[i];
    atomicAdd(&cnt_s[s], 1);
    atomicAdd(&cnt_d[d], 1);
    ebat[i] = node_batch[s];
}
__global__ void count_nodes(const int* __restrict__ node_batch, int* __restrict__ gcnt)
{
    int i = blockIdx.x * blockDim.x + threadIdx.x;
    if (i >= N_NODES) return;
    atomicAdd(&gcnt[node_batch[i]], 1);
}
__global__ __launch_bounds__(1024)
void scan_excl_kernel(const int* __restrict__ cnt, int* __restrict__ off, int n)
{
    __shared__ int part[1024];
    int t = threadIdx.x;
    int chunk = (n + 1023) >> 10;
    int lo = t * chunk; if (lo > n) lo = n;
    int hi = lo + chunk; if (hi > n) hi = n;
    int s = 0;
    for (int i = lo; i < hi; ++i) s += cnt[i];
    part[t] = s;
    __syncthreads();
    for (int d = 1; d < 1024; d <<= 1) {
        int v = (t >= d) ? part[t - d] : 0;
        __syncthreads();
        part[t] += v;
        __syncthreads();
    }
    int base = (t == 0) ? 0 : part[t - 1];
    for (int i = lo; i < hi; ++i) { off[i] = base; base += cnt[i]; }
    if (t == 1023) off[n] = part[1023];
}
__global__ void csr_fill(const int* __restrict__ src, const int* __restrict__ dst,
                         int* __restrict__ cur_s, int* __restrict__ cur_d,
                         int* __restrict__ idx_s, int* __restrict__ idx_d)
{
    int i = blockIdx.x * blockDim.x + threadIdx.x;
    if (i >= N_EDGES) return;
    int p = atomicAdd(&cur_s[src[i]], 1); idx_s[p] = i;
    int q = atomicAdd(&cur_d[dst[i]], 1); idx_d[q] = i;
}
__global__ void seg_sum_csr(const bf16* __restrict__ rows, const int* __restrict__ offs,
                            const int* __restrict__ idx, bf16* __restrict__ out)
{
    int n = blockIdx.x;
    int c = threadIdx.x;
    int k0 = offs[n], k1 = offs[n + 1];
    float s = 0.f;
    for (int k = k0; k < k1; ++k) s += __bfloat162float(rows[(size_t)idx[k] * DD + c]);
    out[(size_t)n * DD + c] = __float2bfloat16(s);
}
__global__ void range_sum(const bf16* __restrict__ rows, const int* __restrict__ gs,
                          bf16* __restrict__ out)
{
    int g = blockIdx.x;
    int c = threadIdx.x;
    int n0 = gs[g], n1 = gs[g + 1];
    float s = 0.f;
    for (int n = n0; n < n1; ++n) s += __bfloat162float(rows[(size_t)n * DD + c]);
    out[(size_t)g * DD + c] = __float2bfloat16(s);
}
__global__ void u_init(bf16* __restrict__ u, const float* __restrict__ u0)
{
    int i = blockIdx.x * blockDim.x + threadIdx.x;
    if (i < N_GRAPH * DD) u[i] = __float2bfloat16(u0[i & (DD - 1)]);
}
__global__ void pos_head2(const bf16* __restrict__ ph, const float* __restrict__ W,
                          const float* __restrict__ b, float* __restrict__ pos,
                          int nrows, int write_mode)
{
    int gid = blockIdx.x * blockDim.x + threadIdx.x;
    int row = gid >> 6;
    int lane = threadIdx.x & 63;
    if (row >= nrows) return;
    const bf16* r = ph + (size_t)row * DD;
    float a0 = 0.f, a1 = 0.f, a2 = 0.f;
    for (int k = lane; k < DD; k += 64) {
        float v = __bfloat162float(r[k]);
        a0 += v * W[k * 3 + 0];
        a1 += v * W[k * 3 + 1];
        a2 += v * W[k * 3 + 2];
    }
#pragma unroll
    for (int d = 32; d > 0; d >>= 1) {
        a0 += __shfl_down(a0, d);
        a1 += __shfl_down(a1, d);
        a2 += __shfl_down(a2, d);
    }
    if (lane == 0) {
        float* p = pos + (size_t)row * 3;
        if (write_mode) {
            p[0] = a0 + b[0]; p[1] = a1 + b[1]; p[2] = a2 + b[2];
        } else {
            p[0] += a0 + b[0]; p[1] += a1 + b[1]; p[2] += a2 + b[2];
        }
    }
}

// ---------------------------------------------------------------------------
extern "C" void kernel_launch(void* const* d_in, const int* in_sizes, int n_in,
                              void* d_out, int out_size, void* d_ws, size_t ws_size,
                              hipStream_t stream)
{
    const float* x_raw    = (const float*)d_in[0];
    const float* edge_raw = (const float*)d_in[1];
    const float* u0       = (const float*)d_in[2];
    const float* enW1 = (const float*)d_in[3];  const float* enb1 = (const float*)d_in[4];
    const float* enW2 = (const float*)d_in[5];  const float* enb2 = (const float*)d_in[6];
    const float* enW3 = (const float*)d_in[7];  const float* enb3 = (const float*)d_in[8];
    const float* eeW1 = (const float*)d_in[9];  const float* eeb1 = (const float*)d_in[10];
    const float* eeW2 = (const float*)d_in[11]; const float* eeb2 = (const float*)d_in[12];
    const float* eeW3 = (const float*)d_in[13]; const float* eeb3 = (const float*)d_in[14];
    const float* eW1 = (const float*)d_in[15];  const float* eb1 = (const float*)d_in[16];
    const float* eW2 = (const float*)d_in[17];  const float* eb2 = (const float*)d_in[18];
    const float* eW3 = (const float*)d_in[19];  const float* eb3 = (const float*)d_in[20];
    const float* nW1 = (const float*)d_in[21];  const float* nb1 = (const float*)d_in[22];
    const float* nW2 = (const float*)d_in[23];  const float* nb2 = (const float*)d_in[24];
    const float* nW3 = (const float*)d_in[25];  const float* nb3 = (const float*)d_in[26];
    const float* gW1 = (const float*)d_in[27];  const float* gb1 = (const float*)d_in[28];
    const float* gW2 = (const float*)d_in[29];  const float* gb2 = (const float*)d_in[30];
    const float* gW3 = (const float*)d_in[31];  const float* gb3 = (const float*)d_in[32];
    const float* pW1 = (const float*)d_in[33];  const float* pb1 = (const float*)d_in[34];
    const float* pW2 = (const float*)d_in[35];  const float* pb2 = (const float*)d_in[36];
    const int* edge_index = (const int*)d_in[37];
    const int* node_batch = (const int*)d_in[38];
    const int* src = edge_index;
    const int* dst = edge_index + N_EDGES;
    float* pos = (float*)d_out;
    (void)ws_size; (void)in_sizes; (void)n_in; (void)out_size;

    // ---- workspace carve (~236 MB) ----
    char* wp = (char*)d_ws;
    auto alloc = [&](size_t bytes) -> void* {
        void* r = (void*)wp;
        wp += (bytes + 255) & ~(size_t)255;
        return r;
    };
    bf16* x     = (bf16*)alloc((size_t)N_NODES * DD * 2);
    bf16* e     = (bf16*)alloc((size_t)N_EDGES * DD * 2);
    bf16* u     = (bf16*)alloc((size_t)N_GRAPH * DD * 2);
    bf16* h1    = (bf16*)alloc((size_t)RCH * HH * 2);
    bf16* h2    = (bf16*)alloc((size_t)RCH * HH * 2);
    bf16* sent  = (bf16*)alloc((size_t)N_NODES * DD * 2);
    bf16* recv  = (bf16*)alloc((size_t)N_NODES * DD * 2);
    bf16* gn    = (bf16*)alloc((size_t)N_GRAPH * DD * 2);
    bf16* ge    = (bf16*)alloc((size_t)N_GRAPH * DD * 2);
    bf16* gh1   = (bf16*)alloc((size_t)N_GRAPH * HH * 2);
    bf16* gh2   = (bf16*)alloc((size_t)N_GRAPH * HH * 2);
    bf16* wbuf  = (bf16*)alloc((size_t)6000000 * 2);        // hi/lo transposed weights (per-layer, reused)
    bf16* rawp  = (bf16*)alloc((size_t)RCH * 192 * 2);      // padded raw-input chunk
    int* cnt_s  = (int*)alloc((size_t)N_NODES * 4);
    int* cnt_d  = (int*)alloc((size_t)N_NODES * 4);
    int* gcnt   = (int*)alloc((size_t)N_GRAPH * 4);
    int* off_s  = (int*)alloc((size_t)(N_NODES + 1) * 4);
    int* off_d  = (int*)alloc((size_t)(N_NODES + 1) * 4);
    int* gstart = (int*)alloc((size_t)(N_GRAPH + 1) * 4);
    int* cur_s  = (int*)alloc((size_t)N_NODES * 4);
    int* cur_d  = (int*)alloc((size_t)N_NODES * 4);
    int* idx_s  = (int*)alloc((size_t)N_EDGES * 4);
    int* idx_d  = (int*)alloc((size_t)N_EDGES * 4);
    int* ebat   = (int*)alloc((size_t)N_EDGES * 4);

    // ---- graph structure (rebuilt every call) ----
    zero_i32<<<(N_NODES + 255) / 256, 256, 0, stream>>>(cnt_s, N_NODES);
    zero_i32<<<(N_NODES + 255) / 256, 256, 0, stream>>>(cnt_d, N_NODES);
    zero_i32<<<(N_GRAPH + 255) / 256, 256, 0, stream>>>(gcnt, N_GRAPH);
    count_edges<<<(N_EDGES + 255) / 256, 256, 0, stream>>>(src, dst, node_batch, cnt_s, cnt_d, ebat);
    count_nodes<<<(N_NODES + 255) / 256, 256, 0, stream>>>(node_batch, gcnt);
    scan_excl_kernel<<<1, 1024, 0, stream>>>(cnt_s, off_s, N_NODES);
    scan_excl_kernel<<<1, 1024, 0, stream>>>(cnt_d, off_d, N_NODES);
    scan_excl_kernel<<<1, 1024, 0, stream>>>(gcnt, gstart, N_GRAPH);
    copy_i32<<<(N_NODES + 255) / 256, 256, 0, stream>>>(off_s, cur_s, N_NODES);
    copy_i32<<<(N_NODES + 255) / 256, 256, 0, stream>>>(off_d, cur_d, N_NODES);
    csr_fill<<<(N_EDGES + 255) / 256, 256, 0, stream>>>(src, dst, cur_s, cur_d, idx_s, idx_d);

    u_init<<<(N_GRAPH * DD + 255) / 256, 256, 0, stream>>>(u, u0);

    // weight-conversion helper: converts W[K][N] -> hi/lo [N][Kp] in wbuf
    bf16* wb_cur = wbuf;
    auto wreset = [&]() { wb_cur = wbuf; };
    auto wconv = [&](const float* W, int N, int K, int Kp) -> bf16* {
        bf16* hi = wb_cur;
        bf16* lo = wb_cur + (size_t)N * Kp;
        wb_cur += (size_t)N * Kp * 2;
        int tot = N * Kp;
        conv_w<<<(tot + 255) / 256, 256, 0, stream>>>(W, N, K, Kp, hi, lo);
        return hi;
    };
    auto wlo_of = [&](bf16* hi, int N, int Kp) -> bf16* { return hi + (size_t)N * Kp; };

    // ---- encoders ----
    wreset();
    bf16* cenW1 = wconv(enW1, HH, NODE_IN_F, 192);
    bf16* cenW2 = wconv(enW2, HH, HH, HH);
    bf16* cenW3 = wconv(enW3, DD, HH, HH);
    bf16* ceeW1 = wconv(eeW1, HH, EDGE_IN_F, 32);
    bf16* ceeW2 = wconv(eeW2, HH, HH, HH);
    bf16* ceeW3 = wconv(eeW3, DD, HH, HH);

    for (int off = 0; off < N_NODES; off += RCH) {
        int cnt = RCH;
        pad_raw<<<(cnt * 192 + 255) / 256, 256, 0, stream>>>(x_raw + (size_t)off * NODE_IN_F, NODE_IN_F, 192, cnt, rawp);
        { GMArgs g = gm_new(cnt, HH); gm_part(g, rawp, 192, nullptr, cenW1, wlo_of(cenW1, HH, 192), 192, 192);
          gm_run(stream, g, enb1, nullptr, h1, 1); }
        { GMArgs g = gm_new(cnt, HH); gm_part(g, h1, HH, nullptr, cenW2, wlo_of(cenW2, HH, HH), HH, HH);
          gm_run(stream, g, enb2, nullptr, h2, 1); }
        { GMArgs g = gm_new(cnt, DD); gm_part(g, h2, HH, nullptr, cenW3, wlo_of(cenW3, DD, HH), HH, HH);
          gm_run(stream, g, enb3, nullptr, x + (size_t)off * DD, 1); }
    }
    for (int off = 0; off < N_EDGES; off += RCH) {
        int cnt = RCH;
        pad_raw<<<(cnt * 32 + 255) / 256, 256, 0, stream>>>(edge_raw + (size_t)off * EDGE_IN_F, EDGE_IN_F, 32, cnt, rawp);
        { GMArgs g = gm_new(cnt, HH); gm_part(g, rawp, 32, nullptr, ceeW1, wlo_of(ceeW1, HH, 32), 32, 32);
          gm_run(stream, g, eeb1, nullptr, h1, 1); }
        { GMArgs g = gm_new(cnt, HH); gm_part(g, h1, HH, nullptr, ceeW2, wlo_of(ceeW2, HH, HH), HH, HH);
          gm_run(stream, g, eeb2, nullptr, h2, 1); }
        { GMArgs g = gm_new(cnt, DD); gm_part(g, h2, HH, nullptr, ceeW3, wlo_of(ceeW3, DD, HH), HH, HH);
          gm_run(stream, g, eeb3, nullptr, e + (size_t)off * DD, 1); }
    }

    // ---- L message-passing layers ----
    for (int l = 0; l < LL; ++l) {
        const float* ew1  = eW1 + (size_t)l * 4 * DD * HH;  const float* eb1l = eb1 + (size_t)l * HH;
        const float* ew2  = eW2 + (size_t)l * HH * HH;      const float* eb2l = eb2 + (size_t)l * HH;
        const float* ew3  = eW3 + (size_t)l * HH * DD;      const float* eb3l = eb3 + (size_t)l * DD;
        const float* nw1  = nW1 + (size_t)l * 4 * DD * HH;  const float* nb1l = nb1 + (size_t)l * HH;
        const float* nw2  = nW2 + (size_t)l * HH * HH;      const float* nb2l = nb2 + (size_t)l * HH;
        const float* nw3  = nW3 + (size_t)l * HH * DD;      const float* nb3l = nb3 + (size_t)l * DD;
        const float* gw1  = gW1 + (size_t)l * 3 * DD * HH;  const float* gb1l = gb1 + (size_t)l * HH;
        const float* gw2  = gW2 + (size_t)l * HH * HH;      const float* gb2l = gb2 + (size_t)l * HH;
        const float* gw3  = gW3 + (size_t)l * HH * DD;      const float* gb3l = gb3 + (size_t)l * DD;
        const float* pw1  = pW1 + (size_t)l * DD * DD;      const float* pb1l = pb1 + (size_t)l * DD;
        const float* pw2  = pW2 + (size_t)l * DD * 3;       const float* pb2l = pb2 + (size_t)l * 3;

        // convert this layer's weights (transposed, hi/lo)
        wreset();
        bf16* cew1 = wconv(ew1, HH, 4 * DD, 4 * DD);   // [512][1024]
        bf16* cew2 = wconv(ew2, HH, HH, HH);
        bf16* cew3 = wconv(ew3, DD, HH, HH);
        bf16* cnw1 = wconv(nw1, HH, 4 * DD, 4 * DD);
        bf16* cnw2 = wconv(nw2, HH, HH, HH);
        bf16* cnw3 = wconv(nw3, DD, HH, HH);
        bf16* cgw1 = wconv(gw1, HH, 3 * DD, 3 * DD);   // [512][768]
        bf16* cgw2 = wconv(gw2, HH, HH, HH);
        bf16* cgw3 = wconv(gw3, DD, HH, HH);
        bf16* cpw1 = wconv(pw1, DD, DD, DD);
        bf16* lew1 = wlo_of(cew1, HH, 4 * DD);
        bf16* lnw1 = wlo_of(cnw1, HH, 4 * DD);
        bf16* lgw1 = wlo_of(cgw1, HH, 3 * DD);

        // ---- edge update: e += MLP3(concat[e, x[src], x[dst], u[eb]]) ----
        for (int off = 0; off < N_EDGES; off += RCH) {
            int cnt = RCH;
            { GMArgs g = gm_new(cnt, HH);
              gm_part(g, e + (size_t)off * DD, DD, nullptr,    cew1,            lew1,            4 * DD, DD);
              gm_part(g, x,                    DD, src + off,  cew1 + 1 * DD,   lew1 + 1 * DD,   4 * DD, DD);
              gm_part(g, x,                    DD, dst + off,  cew1 + 2 * DD,   lew1 + 2 * DD,   4 * DD, DD);
              gm_part(g, u,                    DD, ebat + off, cew1 + 3 * DD,   lew1 + 3 * DD,   4 * DD, DD);
              gm_run(stream, g, eb1l, nullptr, h1, 1); }
            { GMArgs g = gm_new(cnt, HH); gm_part(g, h1, HH, nullptr, cew2, wlo_of(cew2, HH, HH), HH, HH);
              gm_run(stream, g, eb2l, nullptr, h2, 1); }
            { GMArgs g = gm_new(cnt, DD); gm_part(g, h2, HH, nullptr, cew3, wlo_of(cew3, DD, HH), HH, HH);
              gm_run(stream, g, eb3l, e + (size_t)off * DD, e + (size_t)off * DD, 1); }
        }

        // ---- node update ----
        seg_sum_csr<<<N_NODES, 256, 0, stream>>>(e, off_s, idx_s, sent);
        seg_sum_csr<<<N_NODES, 256, 0, stream>>>(e, off_d, idx_d, recv);
        for (int off = 0; off < N_NODES; off += RCH) {
            int cnt = RCH;
            { GMArgs g = gm_new(cnt, HH);
              gm_part(g, x    + (size_t)off * DD, DD, nullptr,          cnw1,          lnw1,          4 * DD, DD);
              gm_part(g, sent + (size_t)off * DD, DD, nullptr,          cnw1 + 1 * DD, lnw1 + 1 * DD, 4 * DD, DD);
              gm_part(g, recv + (size_t)off * DD, DD, nullptr,          cnw1 + 2 * DD, lnw1 + 2 * DD, 4 * DD, DD);
              gm_part(g, u,                       DD, node_batch + off, cnw1 + 3 * DD, lnw1 + 3 * DD, 4 * DD, DD);
              gm_run(stream, g, nb1l, nullptr, h1, 1); }
            { GMArgs g = gm_new(cnt, HH); gm_part(g, h1, HH, nullptr, cnw2, wlo_of(cnw2, HH, HH), HH, HH);
              gm_run(stream, g, nb2l, nullptr, h2, 1); }
            { GMArgs g = gm_new(cnt, DD); gm_part(g, h2, HH, nullptr, cnw3, wlo_of(cnw3, DD, HH), HH, HH);
              gm_run(stream, g, nb3l, x + (size_t)off * DD, x + (size_t)off * DD, 1); }
        }

        // ---- global update (ge == range-sum of `sent`) ----
        range_sum<<<N_GRAPH, 256, 0, stream>>>(x, gstart, gn);
        range_sum<<<N_GRAPH, 256, 0, stream>>>(sent, gstart, ge);
        { GMArgs g = gm_new(N_GRAPH, HH);
          gm_part(g, u,  DD, nullptr, cgw1,          lgw1,          3 * DD, DD);
          gm_part(g, gn, DD, nullptr, cgw1 + 1 * DD, lgw1 + 1 * DD, 3 * DD, DD);
          gm_part(g, ge, DD, nullptr, cgw1 + 2 * DD, lgw1 + 2 * DD, 3 * DD, DD);
          gm_run(stream, g, gb1l, nullptr, gh1, 1); }
        { GMArgs g = gm_new(N_GRAPH, HH); gm_part(g, gh1, HH, nullptr, cgw2, wlo_of(cgw2, HH, HH), HH, HH);
          gm_run(stream, g, gb2l, nullptr, gh2, 1); }
        { GMArgs g = gm_new(N_GRAPH, DD); gm_part(g, gh2, HH, nullptr, cgw3, wlo_of(cgw3, DD, HH), HH, HH);
          gm_run(stream, g, gb3l, u, u, 1); }

        // ---- position head (h1 reused as [cnt][DD]) ----
        for (int off = 0; off < N_NODES; off += RCH) {
            int cnt = RCH;
            { GMArgs g = gm_new(cnt, DD); gm_part(g, x + (size_t)off * DD, DD, nullptr, cpw1, wlo_of(cpw1, DD, DD), DD, DD);
              gm_run(stream, g, pb1l, nullptr, h1, 1); }
            pos_head2<<<((size_t)cnt * 64 + 255) / 256, 256, 0, stream>>>(
                h1, pw2, pb2l, pos + (size_t)off * 3, cnt, l == 0 ? 1 : 0);
        }
    }
}

// Round 4
// 36367.834 us; speedup vs baseline: 4.7426x; 1.0681x over previous
//
#include <hip/hip_runtime.h>
#include <hip/hip_bf16.h>
#include <cstdint>
#include <cstddef>

#define N_NODES 50000
#define N_EDGES 200000
#define N_GRAPH 2048
#define DD 256
#define HH 512
#define LL 12
#define NODE_IN_F 173
#define EDGE_IN_F 13
#define RCH 12500   // row chunk (nodes: 4 chunks, edges: 16 chunks)

typedef __hip_bfloat16 bf16;
typedef __attribute__((ext_vector_type(8))) short short8;
typedef __attribute__((ext_vector_type(4))) float f32x4;

// async global->LDS 16B per lane; LDS dest = wave-uniform base + lane*16
__device__ __forceinline__ void gld16(const void* g, void* l) {
    __builtin_amdgcn_global_load_lds(
        (const __attribute__((address_space(1))) unsigned int*)g,
        (__attribute__((address_space(3))) unsigned int*)l, 16, 0, 0);
}

// ---------------------------------------------------------------------------
// MFMA multi-part gather GEMM with hi/lo-split bf16 weights.
//   C[M,N] = act( sum_p A_p[idx_p? idx_p[r]:r, :Kp] @ (Whi_p + Wlo_p)^T + bias ) (+res)
// A_p bf16 row-major [.,lda]; Whi/Wlo bf16 [N][ldw] (transposed weights, K-padded).
// LDS tiles are contiguous [row][32] shorts (global_load_lds requirement).
// ---------------------------------------------------------------------------
#define TBM 128
#define TBN 128

struct GMArgs {
    const bf16* A[4];
    const int*  idx[4];
    const bf16* whi[4];
    const bf16* wlo[4];
    int lda[4];
    int ldw[4];
    int Kp[4];
    int nparts;
    int M, N;            // ldc == N
    const float* bias;
    const bf16* res;     // row stride N
    bf16* C;
    int relu;
};

__global__ __launch_bounds__(256)
void gemm_mfma(GMArgs g)
{
    __shared__ __align__(16) short As[TBM * 32];
    __shared__ __align__(16) short Bh[TBN * 32];
    __shared__ __align__(16) short Bl[TBN * 32];

    const int tid  = threadIdx.x;
    const int lane = tid & 63;
    const int wv   = tid >> 6;
    const int wm   = (wv >> 1) * 64;   // wave row offset in tile
    const int wn   = (wv & 1) * 64;    // wave col offset in tile
    const int quad = lane >> 4;
    const int l16  = lane & 15;
    const int rq   = lane >> 2;        // staging: row-within-slab 0..15
    const int qq   = lane & 3;         // staging: 16B quarter 0..3
    const int row0 = blockIdx.y * TBM;
    const int col0 = blockIdx.x * TBN;

    f32x4 acc[4][4];
#pragma unroll
    for (int i = 0; i < 4; ++i)
#pragma unroll
        for (int j = 0; j < 4; ++j)
            acc[i][j] = (f32x4){0.f, 0.f, 0.f, 0.f};

    for (int p = 0; p < g.nparts; ++p) {
        const short* Ap  = (const short*)g.A[p];
        const short* Whi = (const short*)g.whi[p];
        const short* Wlo = (const short*)g.wlo[p];
        const int* idx = g.idx[p];
        const int lda = g.lda[p];
        const int ldw = g.ldw[p];
        const int Kp  = g.Kp[p];

        for (int k0 = 0; k0 < Kp; k0 += 32) {
            __syncthreads();   // previous iteration's LDS readers done
            int kcol = k0 + qq * 8;
#pragma unroll
            for (int s = 0; s < 2; ++s) {
                int r = wv * 32 + s * 16 + rq;        // tile row (A) / tile col (B)
                int slab = (wv * 32 + s * 16) * 32;   // LDS short offset of slab base
                // A (possibly gathered rows)
                int gr = row0 + r;
                if (gr < g.M) {
                    int ar = idx ? idx[gr] : gr;
                    gld16(Ap + (size_t)ar * lda + kcol, (short*)As + slab);
                }
                // B hi/lo (cols always in range: N multiple of 128)
                size_t wo = (size_t)(col0 + r) * ldw + kcol;
                gld16(Whi + wo, (short*)Bh + slab);
                gld16(Wlo + wo, (short*)Bl + slab);
            }
            __syncthreads();   // staging visible (compiler drains vmcnt before barrier)

            short8 a[4], bh[4], bl[4];
#pragma unroll
            for (int i = 0; i < 4; ++i)
                a[i] = *(const short8*)&As[(wm + i * 16 + l16) * 32 + quad * 8];
#pragma unroll
            for (int j = 0; j < 4; ++j) {
                bh[j] = *(const short8*)&Bh[(wn + j * 16 + l16) * 32 + quad * 8];
                bl[j] = *(const short8*)&Bl[(wn + j * 16 + l16) * 32 + quad * 8];
            }
#pragma unroll
            for (int i = 0; i < 4; ++i)
#pragma unroll
                for (int j = 0; j < 4; ++j)
                    acc[i][j] = __builtin_amdgcn_mfma_f32_16x16x32_bf16(a[i], bh[j], acc[i][j], 0, 0, 0);
#pragma unroll
            for (int i = 0; i < 4; ++i)
#pragma unroll
                for (int j = 0; j < 4; ++j)
                    acc[i][j] = __builtin_amdgcn_mfma_f32_16x16x32_bf16(a[i], bl[j], acc[i][j], 0, 0, 0);
        }
    }

    // epilogue: C/D frag mapping col=lane&15, row=quad*4+reg
#pragma unroll
    for (int j = 0; j < 4; ++j) {
        int c = col0 + wn + j * 16 + l16;
        float bc = g.bias ? g.bias[c] : 0.f;
#pragma unroll
        for (int i = 0; i < 4; ++i) {
            int rbase = row0 + wm + i * 16 + quad * 4;
#pragma unroll
            for (int r = 0; r < 4; ++r) {
                int gr = rbase + r;
                if (gr >= g.M) continue;
                float v = acc[i][j][r] + bc;
                if (g.relu) v = fmaxf(v, 0.f);
                size_t o = (size_t)gr * g.N + c;
                if (g.res) v += __bfloat162float(g.res[o]);
                g.C[o] = __float2bfloat16(v);
            }
        }
    }
}

// host-side builders
static inline GMArgs gm_new(int M, int N) {
    GMArgs g;
    for (int i = 0; i < 4; ++i) { g.A[i] = nullptr; g.idx[i] = nullptr; g.whi[i] = nullptr; g.wlo[i] = nullptr; g.lda[i] = 0; g.ldw[i] = 0; g.Kp[i] = 0; }
    g.nparts = 0; g.M = M; g.N = N; g.bias = nullptr; g.res = nullptr; g.C = nullptr; g.relu = 0;
    return g;
}
static inline void gm_part(GMArgs& g, const bf16* A, int lda, const int* idx,
                           const bf16* whi, const bf16* wlo, int ldw, int Kp) {
    int p = g.nparts++;
    g.A[p] = A; g.lda[p] = lda; g.idx[p] = idx; g.whi[p] = whi; g.wlo[p] = wlo; g.ldw[p] = ldw; g.Kp[p] = Kp;
}
static inline void gm_run(hipStream_t s, GMArgs& g, const float* bias,
                          const bf16* res, bf16* C, int relu) {
    g.bias = bias; g.res = res; g.C = C; g.relu = relu;
    dim3 grid(g.N / TBN, (g.M + TBM - 1) / TBM);
    gemm_mfma<<<grid, dim3(256), 0, s>>>(g);
}

// ---------------------------------------------------------------------------
// batched weight convert: W fp32 [K][N] -> Whi/Wlo bf16 [N][Kp] (transposed, padded)
// ---------------------------------------------------------------------------
struct ConvDesc { const float* W; bf16* hi; int N, K, Kp, total; };
struct ConvBatch { ConvDesc d[10]; int nd; int grand; };

__global__ void conv_multi(ConvBatch cb)
{
    int i = blockIdx.x * blockDim.x + threadIdx.x;
    if (i >= cb.grand) return;
    int m = 0;
    while (i >= cb.d[m].total) { i -= cb.d[m].total; ++m; }
    const ConvDesc d = cb.d[m];
    int n = i / d.Kp, k = i % d.Kp;
    float v = (k < d.K) ? d.W[(size_t)k * d.N + n] : 0.f;
    bf16 h = __float2bfloat16(v);
    d.hi[i] = h;
    (d.hi + (size_t)d.N * d.Kp)[i] = __float2bfloat16(v - __bfloat162float(h));
}

// pad raw fp32 rows [rows][K] -> bf16 [rows][Kp] zero-padded
__global__ void pad_raw(const float* __restrict__ src, int K, int Kp, int rows,
                        bf16* __restrict__ out)
{
    int i = blockIdx.x * blockDim.x + threadIdx.x;
    if (i >= rows * Kp) return;
    int r = i / Kp, k = i % Kp;
    out[i] = __float2bfloat16(k < K ? src[(size_t)r * K + k] : 0.f);
}

// ---------------------------------------------------------------------------
// graph structure helpers
// ---------------------------------------------------------------------------
__global__ void zero_i32(int* __restrict__ p, int n) {
    int i = blockIdx.x * blockDim.x + threadIdx.x;
    if (i < n) p[i] = 0;
}
__global__ void copy_i32(const int* __restrict__ a, int* __restrict__ b, int n) {
    int i = blockIdx.x * blockDim.x + threadIdx.x;
    if (i < n) b[i] = a[i];
}
__global__ void count_edges(const int* __restrict__ src, const int* __restrict__ dst,
                            const int* __restrict__ node_batch,
                            int* __restrict__ cnt_s, int* __restrict__ cnt_d,
                            int* __restrict__ ebat)
{
    int i = blockIdx.x * blockDim.x + threadIdx.x;
    if (i >= N_EDGES) return;
    int s = src[i], d = dst[i];
    atomicAdd(&cnt_s[s], 1);
    atomicAdd(&cnt_d[d], 1);
    ebat[i] = node_batch[s];
}
__global__ void count_nodes(const int* __restrict__ node_batch, int* __restrict__ gcnt)
{
    int i = blockIdx.x * blockDim.x + threadIdx.x;
    if (i >= N_NODES) return;
    atomicAdd(&gcnt[node_batch[i]], 1);
}
__global__ __launch_bounds__(1024)
void scan_excl_kernel(const int* __restrict__ cnt, int* __restrict__ off, int n)
{
    __shared__ int part[1024];
    int t = threadIdx.x;
    int chunk = (n + 1023) >> 10;
    int lo = t * chunk; if (lo > n) lo = n;
    int hi = lo + chunk; if (hi > n) hi = n;
    int s = 0;
    for (int i = lo; i < hi; ++i) s += cnt[i];
    part[t] = s;
    __syncthreads();
    for (int d = 1; d < 1024; d <<= 1) {
        int v = (t >= d) ? part[t - d] : 0;
        __syncthreads();
        part[t] += v;
        __syncthreads();
    }
    int base = (t == 0) ? 0 : part[t - 1];
    for (int i = lo; i < hi; ++i) { off[i] = base; base += cnt[i]; }
    if (t == 1023) off[n] = part[1023];
}
__global__ void csr_fill(const int* __restrict__ src, const int* __restrict__ dst,
                         int* __restrict__ cur_s, int* __restrict__ cur_d,
                         int* __restrict__ idx_s, int* __restrict__ idx_d)
{
    int i = blockIdx.x * blockDim.x + threadIdx.x;
    if (i >= N_EDGES) return;
    int p = atomicAdd(&cur_s[src[i]], 1); idx_s[p] = i;
    int q = atomicAdd(&cur_d[dst[i]], 1); idx_d[q] = i;
}
__global__ void seg_sum_csr(const bf16* __restrict__ rows, const int* __restrict__ offs,
                            const int* __restrict__ idx, bf16* __restrict__ out)
{
    int n = blockIdx.x;
    int c = threadIdx.x;
    int k0 = offs[n], k1 = offs[n + 1];
    float s = 0.f;
    for (int k = k0; k < k1; ++k) s += __bfloat162float(rows[(size_t)idx[k] * DD + c]);
    out[(size_t)n * DD + c] = __float2bfloat16(s);
}
__global__ void range_sum(const bf16* __restrict__ rows, const int* __restrict__ gs,
                          bf16* __restrict__ out)
{
    int g = blockIdx.x;
    int c = threadIdx.x;
    int n0 = gs[g], n1 = gs[g + 1];
    float s = 0.f;
    for (int n = n0; n < n1; ++n) s += __bfloat162float(rows[(size_t)n * DD + c]);
    out[(size_t)g * DD + c] = __float2bfloat16(s);
}
__global__ void u_init(bf16* __restrict__ u, const float* __restrict__ u0)
{
    int i = blockIdx.x * blockDim.x + threadIdx.x;
    if (i < N_GRAPH * DD) u[i] = __float2bfloat16(u0[i & (DD - 1)]);
}
__global__ void pos_head2(const bf16* __restrict__ ph, const float* __restrict__ W,
                          const float* __restrict__ b, float* __restrict__ pos,
                          int nrows, int write_mode)
{
    int gid = blockIdx.x * blockDim.x + threadIdx.x;
    int row = gid >> 6;
    int lane = threadIdx.x & 63;
    if (row >= nrows) return;
    const bf16* r = ph + (size_t)row * DD;
    float a0 = 0.f, a1 = 0.f, a2 = 0.f;
    for (int k = lane; k < DD; k += 64) {
        float v = __bfloat162float(r[k]);
        a0 += v * W[k * 3 + 0];
        a1 += v * W[k * 3 + 1];
        a2 += v * W[k * 3 + 2];
    }
#pragma unroll
    for (int d = 32; d > 0; d >>= 1) {
        a0 += __shfl_down(a0, d);
        a1 += __shfl_down(a1, d);
        a2 += __shfl_down(a2, d);
    }
    if (lane == 0) {
        float* p = pos + (size_t)row * 3;
        if (write_mode) {
            p[0] = a0 + b[0]; p[1] = a1 + b[1]; p[2] = a2 + b[2];
        } else {
            p[0] += a0 + b[0]; p[1] += a1 + b[1]; p[2] += a2 + b[2];
        }
    }
}

// ---------------------------------------------------------------------------
extern "C" void kernel_launch(void* const* d_in, const int* in_sizes, int n_in,
                              void* d_out, int out_size, void* d_ws, size_t ws_size,
                              hipStream_t stream)
{
    const float* x_raw    = (const float*)d_in[0];
    const float* edge_raw = (const float*)d_in[1];
    const float* u0       = (const float*)d_in[2];
    const float* enW1 = (const float*)d_in[3];  const float* enb1 = (const float*)d_in[4];
    const float* enW2 = (const float*)d_in[5];  const float* enb2 = (const float*)d_in[6];
    const float* enW3 = (const float*)d_in[7];  const float* enb3 = (const float*)d_in[8];
    const float* eeW1 = (const float*)d_in[9];  const float* eeb1 = (const float*)d_in[10];
    const float* eeW2 = (const float*)d_in[11]; const float* eeb2 = (const float*)d_in[12];
    const float* eeW3 = (const float*)d_in[13]; const float* eeb3 = (const float*)d_in[14];
    const float* eW1 = (const float*)d_in[15];  const float* eb1 = (const float*)d_in[16];
    const float* eW2 = (const float*)d_in[17];  const float* eb2 = (const float*)d_in[18];
    const float* eW3 = (const float*)d_in[19];  const float* eb3 = (const float*)d_in[20];
    const float* nW1 = (const float*)d_in[21];  const float* nb1 = (const float*)d_in[22];
    const float* nW2 = (const float*)d_in[23];  const float* nb2 = (const float*)d_in[24];
    const float* nW3 = (const float*)d_in[25];  const float* nb3 = (const float*)d_in[26];
    const float* gW1 = (const float*)d_in[27];  const float* gb1 = (const float*)d_in[28];
    const float* gW2 = (const float*)d_in[29];  const float* gb2 = (const float*)d_in[30];
    const float* gW3 = (const float*)d_in[31];  const float* gb3 = (const float*)d_in[32];
    const float* pW1 = (const float*)d_in[33];  const float* pb1 = (const float*)d_in[34];
    const float* pW2 = (const float*)d_in[35];  const float* pb2 = (const float*)d_in[36];
    const int* edge_index = (const int*)d_in[37];
    const int* node_batch = (const int*)d_in[38];
    const int* src = edge_index;
    const int* dst = edge_index + N_EDGES;
    float* pos = (float*)d_out;
    (void)ws_size; (void)in_sizes; (void)n_in; (void)out_size;

    // ---- workspace carve (~236 MB, same as round 3) ----
    char* wp = (char*)d_ws;
    auto alloc = [&](size_t bytes) -> void* {
        void* r = (void*)wp;
        wp += (bytes + 255) & ~(size_t)255;
        return r;
    };
    bf16* x     = (bf16*)alloc((size_t)N_NODES * DD * 2);
    bf16* e     = (bf16*)alloc((size_t)N_EDGES * DD * 2);
    bf16* u     = (bf16*)alloc((size_t)N_GRAPH * DD * 2);
    bf16* h1    = (bf16*)alloc((size_t)RCH * HH * 2);
    bf16* h2    = (bf16*)alloc((size_t)RCH * HH * 2);
    bf16* sent  = (bf16*)alloc((size_t)N_NODES * DD * 2);
    bf16* recv  = (bf16*)alloc((size_t)N_NODES * DD * 2);
    bf16* gn    = (bf16*)alloc((size_t)N_GRAPH * DD * 2);
    bf16* ge    = (bf16*)alloc((size_t)N_GRAPH * DD * 2);
    bf16* gh1   = (bf16*)alloc((size_t)N_GRAPH * HH * 2);
    bf16* gh2   = (bf16*)alloc((size_t)N_GRAPH * HH * 2);
    bf16* wbuf  = (bf16*)alloc((size_t)6000000 * 2);        // hi/lo transposed weights (per-layer, reused)
    bf16* rawp  = (bf16*)alloc((size_t)RCH * 192 * 2);      // padded raw-input chunk
    int* cnt_s  = (int*)alloc((size_t)N_NODES * 4);
    int* cnt_d  = (int*)alloc((size_t)N_NODES * 4);
    int* gcnt   = (int*)alloc((size_t)N_GRAPH * 4);
    int* off_s  = (int*)alloc((size_t)(N_NODES + 1) * 4);
    int* off_d  = (int*)alloc((size_t)(N_NODES + 1) * 4);
    int* gstart = (int*)alloc((size_t)(N_GRAPH + 1) * 4);
    int* cur_s  = (int*)alloc((size_t)N_NODES * 4);
    int* cur_d  = (int*)alloc((size_t)N_NODES * 4);
    int* idx_s  = (int*)alloc((size_t)N_EDGES * 4);
    int* idx_d  = (int*)alloc((size_t)N_EDGES * 4);
    int* ebat   = (int*)alloc((size_t)N_EDGES * 4);

    // ---- graph structure (rebuilt every call) ----
    zero_i32<<<(N_NODES + 255) / 256, 256, 0, stream>>>(cnt_s, N_NODES);
    zero_i32<<<(N_NODES + 255) / 256, 256, 0, stream>>>(cnt_d, N_NODES);
    zero_i32<<<(N_GRAPH + 255) / 256, 256, 0, stream>>>(gcnt, N_GRAPH);
    count_edges<<<(N_EDGES + 255) / 256, 256, 0, stream>>>(src, dst, node_batch, cnt_s, cnt_d, ebat);
    count_nodes<<<(N_NODES + 255) / 256, 256, 0, stream>>>(node_batch, gcnt);
    scan_excl_kernel<<<1, 1024, 0, stream>>>(cnt_s, off_s, N_NODES);
    scan_excl_kernel<<<1, 1024, 0, stream>>>(cnt_d, off_d, N_NODES);
    scan_excl_kernel<<<1, 1024, 0, stream>>>(gcnt, gstart, N_GRAPH);
    copy_i32<<<(N_NODES + 255) / 256, 256, 0, stream>>>(off_s, cur_s, N_NODES);
    copy_i32<<<(N_NODES + 255) / 256, 256, 0, stream>>>(off_d, cur_d, N_NODES);
    csr_fill<<<(N_EDGES + 255) / 256, 256, 0, stream>>>(src, dst, cur_s, cur_d, idx_s, idx_d);

    u_init<<<(N_GRAPH * DD + 255) / 256, 256, 0, stream>>>(u, u0);

    // batched weight conversion helper
    bf16* wb_cur = wbuf;
    ConvBatch cb; cb.nd = 0; cb.grand = 0;
    auto wreset = [&]() { wb_cur = wbuf; cb.nd = 0; cb.grand = 0; };
    auto wadd = [&](const float* W, int N, int K, int Kp) -> bf16* {
        bf16* hi = wb_cur;
        wb_cur += (size_t)N * Kp * 2;
        ConvDesc& d = cb.d[cb.nd++];
        d.W = W; d.hi = hi; d.N = N; d.K = K; d.Kp = Kp; d.total = N * Kp;
        cb.grand += d.total;
        return hi;
    };
    auto wflush = [&]() {
        conv_multi<<<(cb.grand + 255) / 256, 256, 0, stream>>>(cb);
    };
    auto wlo_of = [&](bf16* hi, int N, int Kp) -> bf16* { return hi + (size_t)N * Kp; };

    // ---- encoders ----
    wreset();
    bf16* cenW1 = wadd(enW1, HH, NODE_IN_F, 192);
    bf16* cenW2 = wadd(enW2, HH, HH, HH);
    bf16* cenW3 = wadd(enW3, DD, HH, HH);
    bf16* ceeW1 = wadd(eeW1, HH, EDGE_IN_F, 32);
    bf16* ceeW2 = wadd(eeW2, HH, HH, HH);
    bf16* ceeW3 = wadd(eeW3, DD, HH, HH);
    wflush();

    for (int off = 0; off < N_NODES; off += RCH) {
        int cnt = RCH;
        pad_raw<<<(cnt * 192 + 255) / 256, 256, 0, stream>>>(x_raw + (size_t)off * NODE_IN_F, NODE_IN_F, 192, cnt, rawp);
        { GMArgs g = gm_new(cnt, HH); gm_part(g, rawp, 192, nullptr, cenW1, wlo_of(cenW1, HH, 192), 192, 192);
          gm_run(stream, g, enb1, nullptr, h1, 1); }
        { GMArgs g = gm_new(cnt, HH); gm_part(g, h1, HH, nullptr, cenW2, wlo_of(cenW2, HH, HH), HH, HH);
          gm_run(stream, g, enb2, nullptr, h2, 1); }
        { GMArgs g = gm_new(cnt, DD); gm_part(g, h2, HH, nullptr, cenW3, wlo_of(cenW3, DD, HH), HH, HH);
          gm_run(stream, g, enb3, nullptr, x + (size_t)off * DD, 1); }
    }
    for (int off = 0; off < N_EDGES; off += RCH) {
        int cnt = RCH;
        pad_raw<<<(cnt * 32 + 255) / 256, 256, 0, stream>>>(edge_raw + (size_t)off * EDGE_IN_F, EDGE_IN_F, 32, cnt, rawp);
        { GMArgs g = gm_new(cnt, HH); gm_part(g, rawp, 32, nullptr, ceeW1, wlo_of(ceeW1, HH, 32), 32, 32);
          gm_run(stream, g, eeb1, nullptr, h1, 1); }
        { GMArgs g = gm_new(cnt, HH); gm_part(g, h1, HH, nullptr, ceeW2, wlo_of(ceeW2, HH, HH), HH, HH);
          gm_run(stream, g, eeb2, nullptr, h2, 1); }
        { GMArgs g = gm_new(cnt, DD); gm_part(g, h2, HH, nullptr, ceeW3, wlo_of(ceeW3, DD, HH), HH, HH);
          gm_run(stream, g, eeb3, nullptr, e + (size_t)off * DD, 1); }
    }

    // ---- L message-passing layers ----
    for (int l = 0; l < LL; ++l) {
        const float* ew1  = eW1 + (size_t)l * 4 * DD * HH;  const float* eb1l = eb1 + (size_t)l * HH;
        const float* ew2  = eW2 + (size_t)l * HH * HH;      const float* eb2l = eb2 + (size_t)l * HH;
        const float* ew3  = eW3 + (size_t)l * HH * DD;      const float* eb3l = eb3 + (size_t)l * DD;
        const float* nw1  = nW1 + (size_t)l * 4 * DD * HH;  const float* nb1l = nb1 + (size_t)l * HH;
        const float* nw2  = nW2 + (size_t)l * HH * HH;      const float* nb2l = nb2 + (size_t)l * HH;
        const float* nw3  = nW3 + (size_t)l * HH * DD;      const float* nb3l = nb3 + (size_t)l * DD;
        const float* gw1  = gW1 + (size_t)l * 3 * DD * HH;  const float* gb1l = gb1 + (size_t)l * HH;
        const float* gw2  = gW2 + (size_t)l * HH * HH;      const float* gb2l = gb2 + (size_t)l * HH;
        const float* gw3  = gW3 + (size_t)l * HH * DD;      const float* gb3l = gb3 + (size_t)l * DD;
        const float* pw1  = pW1 + (size_t)l * DD * DD;      const float* pb1l = pb1 + (size_t)l * DD;
        const float* pw2  = pW2 + (size_t)l * DD * 3;       const float* pb2l = pb2 + (size_t)l * 3;

        // convert this layer's weights (transposed, hi/lo) — one launch
        wreset();
        bf16* cew1 = wadd(ew1, HH, 4 * DD, 4 * DD);   // [512][1024]
        bf16* cew2 = wadd(ew2, HH, HH, HH);
        bf16* cew3 = wadd(ew3, DD, HH, HH);
        bf16* cnw1 = wadd(nw1, HH, 4 * DD, 4 * DD);
        bf16* cnw2 = wadd(nw2, HH, HH, HH);
        bf16* cnw3 = wadd(nw3, DD, HH, HH);
        bf16* cgw1 = wadd(gw1, HH, 3 * DD, 3 * DD);   // [512][768]
        bf16* cgw2 = wadd(gw2, HH, HH, HH);
        bf16* cgw3 = wadd(gw3, DD, HH, HH);
        bf16* cpw1 = wadd(pw1, DD, DD, DD);
        wflush();
        bf16* lew1 = wlo_of(cew1, HH, 4 * DD);
        bf16* lnw1 = wlo_of(cnw1, HH, 4 * DD);
        bf16* lgw1 = wlo_of(cgw1, HH, 3 * DD);

        // ---- edge update: e += MLP3(concat[e, x[src], x[dst], u[eb]]) ----
        for (int off = 0; off < N_EDGES; off += RCH) {
            int cnt = RCH;
            { GMArgs g = gm_new(cnt, HH);
              gm_part(g, e + (size_t)off * DD, DD, nullptr,    cew1,            lew1,            4 * DD, DD);
              gm_part(g, x,                    DD, src + off,  cew1 + 1 * DD,   lew1 + 1 * DD,   4 * DD, DD);
              gm_part(g, x,                    DD, dst + off,  cew1 + 2 * DD,   lew1 + 2 * DD,   4 * DD, DD);
              gm_part(g, u,                    DD, ebat + off, cew1 + 3 * DD,   lew1 + 3 * DD,   4 * DD, DD);
              gm_run(stream, g, eb1l, nullptr, h1, 1); }
            { GMArgs g = gm_new(cnt, HH); gm_part(g, h1, HH, nullptr, cew2, wlo_of(cew2, HH, HH), HH, HH);
              gm_run(stream, g, eb2l, nullptr, h2, 1); }
            { GMArgs g = gm_new(cnt, DD); gm_part(g, h2, HH, nullptr, cew3, wlo_of(cew3, DD, HH), HH, HH);
              gm_run(stream, g, eb3l, e + (size_t)off * DD, e + (size_t)off * DD, 1); }
        }

        // ---- node update ----
        seg_sum_csr<<<N_NODES, 256, 0, stream>>>(e, off_s, idx_s, sent);
        seg_sum_csr<<<N_NODES, 256, 0, stream>>>(e, off_d, idx_d, recv);
        for (int off = 0; off < N_NODES; off += RCH) {
            int cnt = RCH;
            { GMArgs g = gm_new(cnt, HH);
              gm_part(g, x    + (size_t)off * DD, DD, nullptr,          cnw1,          lnw1,          4 * DD, DD);
              gm_part(g, sent + (size_t)off * DD, DD, nullptr,          cnw1 + 1 * DD, lnw1 + 1 * DD, 4 * DD, DD);
              gm_part(g, recv + (size_t)off * DD, DD, nullptr,          cnw1 + 2 * DD, lnw1 + 2 * DD, 4 * DD, DD);
              gm_part(g, u,                       DD, node_batch + off, cnw1 + 3 * DD, lnw1 + 3 * DD, 4 * DD, DD);
              gm_run(stream, g, nb1l, nullptr, h1, 1); }
            { GMArgs g = gm_new(cnt, HH); gm_part(g, h1, HH, nullptr, cnw2, wlo_of(cnw2, HH, HH), HH, HH);
              gm_run(stream, g, nb2l, nullptr, h2, 1); }
            { GMArgs g = gm_new(cnt, DD); gm_part(g, h2, HH, nullptr, cnw3, wlo_of(cnw3, DD, HH), HH, HH);
              gm_run(stream, g, nb3l, x + (size_t)off * DD, x + (size_t)off * DD, 1); }
        }

        // ---- global update (ge == range-sum of `sent`) ----
        range_sum<<<N_GRAPH, 256, 0, stream>>>(x, gstart, gn);
        range_sum<<<N_GRAPH, 256, 0, stream>>>(sent, gstart, ge);
        { GMArgs g = gm_new(N_GRAPH, HH);
          gm_part(g, u,  DD, nullptr, cgw1,          lgw1,          3 * DD, DD);
          gm_part(g, gn, DD, nullptr, cgw1 + 1 * DD, lgw1 + 1 * DD, 3 * DD, DD);
          gm_part(g, ge, DD, nullptr, cgw1 + 2 * DD, lgw1 + 2 * DD, 3 * DD, DD);
          gm_run(stream, g, gb1l, nullptr, gh1, 1); }
        { GMArgs g = gm_new(N_GRAPH, HH); gm_part(g, gh1, HH, nullptr, cgw2, wlo_of(cgw2, HH, HH), HH, HH);
          gm_run(stream, g, gb2l, nullptr, gh2, 1); }
        { GMArgs g = gm_new(N_GRAPH, DD); gm_part(g, gh2, HH, nullptr, cgw3, wlo_of(cgw3, DD, HH), HH, HH);
          gm_run(stream, g, gb3l, u, u, 1); }

        // ---- position head (h1 reused as [cnt][DD]) ----
        for (int off = 0; off < N_NODES; off += RCH) {
            int cnt = RCH;
            { GMArgs g = gm_new(cnt, DD); gm_part(g, x + (size_t)off * DD, DD, nullptr, cpw1, wlo_of(cpw1, DD, DD), DD, DD);
              gm_run(stream, g, pb1l, nullptr, h1, 1); }
            pos_head2<<<((size_t)cnt * 64 + 255) / 256, 256, 0, stream>>>(
                h1, pw2, pb2l, pos + (size_t)off * 3, cnt, l == 0 ? 1 : 0);
        }
    }
}